// Round 12
// baseline (503.284 us; speedup 1.0000x reference)
//
#include <hip/hip_runtime.h>

typedef short short4s __attribute__((ext_vector_type(4)));
typedef short short8 __attribute__((ext_vector_type(8)));
typedef __bf16 bf16x8 __attribute__((ext_vector_type(8)));
typedef float f32x4 __attribute__((ext_vector_type(4)));

#define NFEAT 1024
#define HDIM  64
#define NHEAD 16
#define TC2   2048
#define QSCL  0.18033688011112043f   // log2(e)/8 folded into Q

__device__ __forceinline__ short f2bf(float f) {
    unsigned int u = __builtin_bit_cast(unsigned int, f);
    u += 0x7fffu + ((u >> 16) & 1u);
    return (short)(u >> 16);
}
__device__ __forceinline__ short f2bfq(float f) {
    __bf16 h = (__bf16)f;
    return __builtin_bit_cast(short, h);
}
__device__ __forceinline__ float bf2f(short s) {
    unsigned int u = ((unsigned int)(unsigned short)s) << 16;
    return __builtin_bit_cast(float, u);
}

__device__ __forceinline__ f32x4 mfma_bf16(short8 a, short8 b, f32x4 c) {
    return __builtin_amdgcn_mfma_f32_16x16x32_bf16(
        __builtin_bit_cast(bf16x8, a), __builtin_bit_cast(bf16x8, b), c, 0, 0, 0);
}

#define GLOAD16(gp, lp) __builtin_amdgcn_global_load_lds( \
    (const __attribute__((address_space(1))) void*)(gp),  \
    (__attribute__((address_space(3))) void*)(lp), 16, 0, 0)

// ---------------------------------------------------------------------------
// prep (R10 structure): conversions + cache chunk. Also zeroes the 256
// combine counters (block 0) each launch for graph-replay determinism.
// ---------------------------------------------------------------------------
__global__ __launch_bounds__(256) void prep_kernel(
    const float* __restrict__ q, const float* __restrict__ k, const float* __restrict__ v,
    const float* __restrict__ Wq, const float* __restrict__ Wk,
    const float* __restrict__ Wv, const float* __restrict__ Wo,
    const float4* __restrict__ cache4,
    short* __restrict__ qin, short* __restrict__ kin, short* __restrict__ vin,
    short* __restrict__ wqb, short* __restrict__ wkb, short* __restrict__ wvb,
    short* __restrict__ wob,
    float4* __restrict__ nc4, short* __restrict__ kbb, short* __restrict__ vtb,
    int* __restrict__ cnt)
{
    __shared__ short Vt[64 * 72];
    const int b = blockIdx.x, tid = threadIdx.x;
    if (b == 0 && tid < 256) cnt[tid] = 0;
    if (b < 1280) {
        const float* src; short* dst; size_t base;
        if (b < 256)        { src = q;  dst = qin; base = (size_t)b * 8192; }
        else if (b < 512)   { src = k;  dst = kin; base = (size_t)(b - 256) * 8192; }
        else if (b < 768)   { src = v;  dst = vin; base = (size_t)(b - 512) * 8192; }
        else if (b < 896)   { src = Wq; dst = wqb; base = (size_t)(b - 768) * 8192; }
        else if (b < 1024)  { src = Wk; dst = wkb; base = (size_t)(b - 896) * 8192; }
        else if (b < 1152)  { src = Wv; dst = wvb; base = (size_t)(b - 1024) * 8192; }
        else                { src = Wo; dst = wob; base = (size_t)(b - 1152) * 8192; }
        const size_t off = base + (size_t)tid * 8;
        float4 a[8];
#pragma unroll
        for (int s = 0; s < 4; ++s) {
            a[2*s]   = *(const float4*)(src + off + s * 2048);
            a[2*s+1] = *(const float4*)(src + off + s * 2048 + 4);
        }
#pragma unroll
        for (int s = 0; s < 4; ++s) {
            short8 o;
            o[0] = f2bf(a[2*s].x);   o[1] = f2bf(a[2*s].y);
            o[2] = f2bf(a[2*s].z);   o[3] = f2bf(a[2*s].w);
            o[4] = f2bf(a[2*s+1].x); o[5] = f2bf(a[2*s+1].y);
            o[6] = f2bf(a[2*s+1].z); o[7] = f2bf(a[2*s+1].w);
            *(short8*)(dst + off + s * 2048) = o;
        }
    } else {
        const int cb = b - 1280;                 // 0..511
        const int bh = cb >> 4, t0 = (cb & 15) * 64;
        const int col4 = tid & 31, r0 = tid >> 5;    // rows r0 + 8j
        const float4* src = cache4 + ((size_t)bh * 1024 + t0 + r0) * 32 + col4;
        float4* ncr = nc4 + ((size_t)bh * TC2 + t0 + r0) * 32 + col4;
        float4 a[8];
#pragma unroll
        for (int j = 0; j < 8; ++j) a[j] = src[j * 256];
#pragma unroll
        for (int j = 0; j < 8; ++j) ncr[j * 256] = a[j];
        if (col4 < 16) {                             // K half (c < 64)
#pragma unroll
            for (int j = 0; j < 8; ++j) {
                short4s kp;
                kp[0] = f2bf(a[j].x); kp[1] = f2bf(a[j].y);
                kp[2] = f2bf(a[j].z); kp[3] = f2bf(a[j].w);
                *(short4s*)&kbb[((size_t)bh * TC2 + t0 + r0 + 8 * j) * 64 + col4 * 4] = kp;
            }
        } else {                                     // V half -> LDS transpose
            const int d = (col4 - 16) * 4;
#pragma unroll
            for (int j = 0; j < 8; ++j) {
                int r = r0 + 8 * j;
                Vt[(d + 0) * 72 + r] = f2bf(a[j].x);
                Vt[(d + 1) * 72 + r] = f2bf(a[j].y);
                Vt[(d + 2) * 72 + r] = f2bf(a[j].z);
                Vt[(d + 3) * 72 + r] = f2bf(a[j].w);
            }
        }
        __syncthreads();
        const int d = tid >> 2, seg = (tid & 3) * 16;
        short* vd = &vtb[((size_t)bh * HDIM + d) * TC2 + t0 + seg];
        *(short8*)(vd)     = *(const short8*)&Vt[d * 72 + seg];
        *(short8*)(vd + 8) = *(const short8*)&Vt[d * 72 + seg + 8];
    }
}

// ---------------------------------------------------------------------------
// 64x128 GEMM (R10 multimode), BK=64, global_load_lds staging. y = A W^T + b.
// QKV: grid (8, 32, 3) = 768 blocks (3/CU). O-proj: (8, 32, 1), base_mode=3.
// mode 2 (V) epilogue writes fp32 ncache AND bf16 vtb.
// ---------------------------------------------------------------------------
__global__ __launch_bounds__(256) void gemm64(
    const short* __restrict__ A0, const short* __restrict__ A1, const short* __restrict__ A2,
    const short* __restrict__ W0, const short* __restrict__ W1, const short* __restrict__ W2,
    const float* __restrict__ b0, const float* __restrict__ b1, const float* __restrict__ b2,
    float* __restrict__ outf, short* __restrict__ qbuf, short* __restrict__ kbb,
    short* __restrict__ vtbp, int base_mode)
{
    __shared__ short As[64 * 64];
    __shared__ short Bs[128 * 64];

    int mode;
    const short *A, *W;
    const float* bias;
    if (base_mode == 3) { mode = 3; A = A0; W = W0; bias = b0; }
    else {
        mode = blockIdx.z;
        if (mode == 0)      { A = A0; W = W0; bias = b0; }
        else if (mode == 1) { A = A1; W = W1; bias = b1; }
        else                { A = A2; W = W2; bias = b2; }
    }

    const int tid = threadIdx.x, lane = tid & 63, w = tid >> 6;
    const int lr = lane & 15, lg = lane >> 4;
    const int bx = blockIdx.x, by = blockIdx.y;

    f32x4 acc[4][2];
#pragma unroll
    for (int m = 0; m < 4; ++m)
#pragma unroll
        for (int n = 0; n < 2; ++n) acc[m][n] = (f32x4){0.f, 0.f, 0.f, 0.f};

    const short* agBase = A + (size_t)(by * 64 + w * 16 + (lane >> 3)) * 1024 + (lane & 7) * 8;
    const short* bgBase = W + (size_t)(bx * 128 + w * 32 + (lane >> 3)) * 1024 + (lane & 7) * 8;
    short* asW = &As[w * 1024];
    short* bsW = &Bs[w * 2048];

    for (int kt = 0; kt < 16; ++kt) {
        const short* ag = agBase + kt * 64;
        const short* bg = bgBase + kt * 64;
        GLOAD16(ag,          asW);
        GLOAD16(ag + 8192,   asW + 512);
        GLOAD16(bg,          bsW);
        GLOAD16(bg + 8192,   bsW + 512);
        GLOAD16(bg + 16384,  bsW + 1024);
        GLOAD16(bg + 24576,  bsW + 1536);
        __syncthreads();
#pragma unroll
        for (int kk = 0; kk < 2; ++kk) {
            short8 af[4], bf[2];
#pragma unroll
            for (int m = 0; m < 4; ++m)
                af[m] = *(const short8*)&As[(m * 16 + lr) * 64 + kk * 32 + lg * 8];
#pragma unroll
            for (int n = 0; n < 2; ++n)
                bf[n] = *(const short8*)&Bs[(w * 32 + n * 16 + lr) * 64 + kk * 32 + lg * 8];
#pragma unroll
            for (int m = 0; m < 4; ++m)
#pragma unroll
                for (int n = 0; n < 2; ++n)
                    acc[m][n] = mfma_bf16(af[m], bf[n], acc[m][n]);
        }
        __syncthreads();
    }

#pragma unroll
    for (int m = 0; m < 4; ++m) {
#pragma unroll
        for (int n = 0; n < 2; ++n) {
            const int cg = bx * 128 + w * 32 + n * 16 + lr;
            const int rg0 = by * 64 + m * 16 + lg * 4;
            const float bv = bias[cg];
            if (mode == 3) {
#pragma unroll
                for (int r = 0; r < 4; ++r)
                    outf[(size_t)(rg0 + r) * NFEAT + cg] = acc[m][n][r] + bv;
            } else {
                const int b = rg0 >> 10, t0 = rg0 & 1023;
                const int h = cg >> 6, d = cg & 63;
                const size_t bh = (size_t)b * NHEAD + h;
                if (mode == 0) {
#pragma unroll
                    for (int r = 0; r < 4; ++r)
                        qbuf[(bh * 1024 + t0 + r) * HDIM + d] = f2bf((acc[m][n][r] + bv) * QSCL);
                } else if (mode == 1) {
#pragma unroll
                    for (int r = 0; r < 4; ++r) {
                        float val = acc[m][n][r] + bv;
                        outf[(bh * TC2 + 1024 + t0 + r) * 128 + d] = val;
                        kbb[(bh * TC2 + 1024 + t0 + r) * HDIM + d] = f2bf(val);
                    }
                } else {
                    short4s pk;
#pragma unroll
                    for (int r = 0; r < 4; ++r) {
                        float val = acc[m][n][r] + bv;
                        outf[(bh * TC2 + 1024 + t0 + r) * 128 + 64 + d] = val;
                        pk[r] = f2bf(val);
                    }
                    *(short4s*)&vtbp[(bh * HDIM + d) * TC2 + 1024 + t0] = pk;
                }
            }
        }
    }
}

// ---------------------------------------------------------------------------
// Flash attention v8: R10's v7 (no online max) + FUSED COMBINE. The 4
// quarter-blocks of each (bh,qt) write bf16 partials + l; each fences and
// bumps a device-scope counter; the last arrival acquires and performs the
// combine for its 128 rows inline, writing xb. Deterministic (fixed-order
// sum, independent of arrival order).
// ---------------------------------------------------------------------------
__global__ __launch_bounds__(512) void attn_kernel(
    const short* __restrict__ qb, const short* __restrict__ kb,
    const short* __restrict__ vtb, short* __restrict__ opart,
    float* __restrict__ lbuf, short* __restrict__ xbuf, int* __restrict__ cnt)
{
    __shared__ short Ks[2][64 * 64];
    __shared__ short Vs[2][64 * 64];
    __shared__ short Ps[8][16 * 32];
    __shared__ int s_old;

    const int tid = threadIdx.x, lane = tid & 63, w = tid >> 6;
    const int lr = lane & 15, lg = lane >> 4;
    const int b0 = blockIdx.x;
    const int xcd = b0 & 7, rest = b0 >> 3;           // 8 x 128
    const int unit = xcd + 8 * (rest & 15);           // 0..127 = bh*4 + quarter
    const int qt = rest >> 4;                         // 0..7
    const int bh = unit >> 2, quarter = unit & 3;
    const int xz = lr & 7;

    const short* qrow = qb + ((size_t)bh * 1024 + qt * 128 + w * 16 + lr) * HDIM + lg * 8;
    const short8 bq0 = *(const short8*)(qrow);
    const short8 bq1 = *(const short8*)(qrow + 32);

    const int srow = tid >> 3;
    const int scx = ((tid & 7) ^ (srow & 7)) * 8;
    const short* kgb = kb  + ((size_t)bh * TC2 + quarter * 512 + srow) * HDIM + scx;
    const short* vgb = vtb + ((size_t)bh * HDIM + srow) * TC2 + quarter * 512 + scx;
    short* kdst = &Ks[0][0] + w * 512;
    short* vdst = &Vs[0][0] + w * 512;

#define STAGE(bufsel, kvt_) do {                                         \
        const short* kg_ = kgb + (size_t)(kvt_) * 64 * HDIM;             \
        const short* vg_ = vgb + (kvt_) * 64;                            \
        GLOAD16(kg_, kdst + (bufsel) * 4096);                            \
        GLOAD16(vg_, vdst + (bufsel) * 4096);                            \
    } while (0)

    f32x4 accx[4];
#pragma unroll
    for (int i = 0; i < 4; ++i) accx[i] = (f32x4){0.f, 0.f, 0.f, 0.f};
    float lsp = 0.f;                                  // per-lane l partial
    short* pw = &Ps[w][0];

    STAGE(0, 0);
    __syncthreads();

    int cur = 0;
    for (int kvt = 0; kvt < 8; ++kvt) {
        if (kvt < 7) STAGE(cur ^ 1, kvt + 1);
        const short* Kc = &Ks[cur][0];
        const short* Vc = &Vs[cur][0];

        // ---- S^T = K Q^T ----
        f32x4 s[4];
#pragma unroll
        for (int n = 0; n < 4; ++n) {
            const short* kt = Kc + (n * 16 + lr) * 64;
            short8 k0 = *(const short8*)&kt[(lg ^ xz) * 8];
            short8 k1 = *(const short8*)&kt[((4 + lg) ^ xz) * 8];
            s[n] = (f32x4){0.f, 0.f, 0.f, 0.f};
            s[n] = mfma_bf16(k0, bq0, s[n]);
            s[n] = mfma_bf16(k1, bq1, s[n]);
        }

        // ---- P = exp2(S), per-lane l partial ----
        float p[4][4];
#pragma unroll
        for (int n = 0; n < 4; ++n)
#pragma unroll
            for (int r = 0; r < 4; ++r) p[n][r] = __builtin_amdgcn_exp2f(s[n][r]);
        float sm[8];
#pragma unroll
        for (int i = 0; i < 8; ++i) sm[i] = p[i >> 1][(i & 1) * 2] + p[i >> 1][(i & 1) * 2 + 1];
        lsp += ((sm[0] + sm[1]) + (sm[2] + sm[3])) + ((sm[4] + sm[5]) + (sm[6] + sm[7]));

        // ---- PV per k-slice ----
#pragma unroll
        for (int ks = 0; ks < 2; ++ks) {
            __builtin_amdgcn_sched_barrier(0);
#pragma unroll
            for (int np = 0; np < 2; ++np) {
                int n = 2 * ks + np;
                short4s pk;
                pk[0] = f2bfq(p[n][0]); pk[1] = f2bfq(p[n][1]);
                pk[2] = f2bfq(p[n][2]); pk[3] = f2bfq(p[n][3]);
                int slot = (2 * np + (lg >> 1)) ^ (lr & 3);
                *(short4s*)&pw[lr * 32 + slot * 8 + (lg & 1) * 4] = pk;
            }
            short8 ap = *(const short8*)&pw[lr * 32 + (lg ^ (lr & 3)) * 8];
#pragma unroll
            for (int nd = 0; nd < 4; ++nd) {
                const short* vt = Vc + (nd * 16 + lr) * 64;
                short8 vf = *(const short8*)&vt[((ks * 4 + lg) ^ xz) * 8];
                accx[nd] = mfma_bf16(ap, vf, accx[nd]);
            }
        }

        __syncthreads();
        cur ^= 1;
    }

    // ---- epilogue: bf16 partials + l ----
    float ls = lsp;
    ls += __shfl_xor(ls, 16);
    ls += __shfl_xor(ls, 32);
    const size_t rbase = (size_t)quarter * 32768 + (size_t)bh * 1024 + qt * 128 + w * 16;
#pragma unroll
    for (int nd = 0; nd < 4; ++nd)
#pragma unroll
        for (int r = 0; r < 4; ++r)
            opart[(rbase + lg * 4 + r) * 64 + nd * 16 + lr] = f2bfq(accx[nd][r]);
    if (lg == 0) lbuf[rbase + lr] = ls;

    // ---- fused combine: last of the 4 quarter-blocks does it ----
    __threadfence();                       // release own partials
    __syncthreads();                       // all threads fenced
    if (tid == 0) s_old = atomicAdd(&cnt[bh * 8 + qt], 1);
    __syncthreads();
    if (s_old == 3) {
        __threadfence();                   // acquire others' partials
        const int r_loc = tid >> 2, seg = (tid & 3) * 16;
        const int row = bh * 1024 + qt * 128 + r_loc;          // within [32768]
        float l = lbuf[row] + lbuf[32768 + row] + lbuf[65536 + row] + lbuf[98304 + row];
        float inv = 1.0f / l;
        float a0[8], a1[8];
#pragma unroll
        for (int j = 0; j < 8; ++j) { a0[j] = 0.f; a1[j] = 0.f; }
#pragma unroll
        for (int i = 0; i < 4; ++i) {
            const short* op = &opart[((size_t)i * 32768 + row) * 64 + seg];
            short8 q0 = *(const short8*)op;
            short8 q1 = *(const short8*)(op + 8);
#pragma unroll
            for (int j = 0; j < 8; ++j) { a0[j] += bf2f(q0[j]); a1[j] += bf2f(q1[j]); }
        }
        short8 o0, o1;
#pragma unroll
        for (int j = 0; j < 8; ++j) { o0[j] = f2bfq(a0[j] * inv); o1[j] = f2bfq(a1[j] * inv); }
        const int b_ = bh >> 4, h_ = bh & 15;
        short* xd = &xbuf[((size_t)(b_ * 1024 + qt * 128 + r_loc)) * NFEAT + h_ * 64 + seg];
        *(short8*)xd = o0;
        *(short8*)(xd + 8) = o1;
    }
#undef STAGE
}

// ---------------------------------------------------------------------------
extern "C" void kernel_launch(void* const* d_in, const int* in_sizes, int n_in,
                              void* d_out, int out_size, void* d_ws, size_t ws_size,
                              hipStream_t stream) {
    const float* query = (const float*)d_in[0];
    const float* key   = (const float*)d_in[1];
    const float* value = (const float*)d_in[2];
    const float* cache = (const float*)d_in[3];
    const float* Wq = (const float*)d_in[4];
    const float* bq = (const float*)d_in[5];
    const float* Wk = (const float*)d_in[6];
    const float* bk = (const float*)d_in[7];
    const float* Wv = (const float*)d_in[8];
    const float* bv = (const float*)d_in[9];
    const float* Wo = (const float*)d_in[10];
    const float* bo = (const float*)d_in[11];

    float* out0   = (float*)d_out;
    float* ncache = out0 + (size_t)2 * 1024 * 1024;

    short* qin = (short*)d_ws;                       // 0      (2M shorts)
    short* kin = qin + (size_t)2097152;              // 2M
    short* vin = kin + (size_t)2097152;              // 4M
    short* wqb = vin + (size_t)2097152;              // 6M
    short* wkb = wqb + (size_t)1048576;              // 7M
    short* wvb = wkb + (size_t)1048576;              // 8M
    short* wob = wvb + (size_t)1048576;              // 9M
    short* qbuf = wob + (size_t)1048576;             // 10M (2M)
    short* kbb  = qbuf + (size_t)2097152;            // 12M (4M)
    short* vtb  = kbb  + (size_t)4194304;            // 16M (4M)
    short* xb   = vtb  + (size_t)4194304;            // 20M (2M) -- NOT overlaid
    int*   cnt  = (int*)(xb + (size_t)2097152);      // 22M shorts = 44MB (1KB)
    // Overlays (regions dead by the time attn runs):
    short* opart = (short*)d_ws;                     // [4][32768][64] bf16 = 8M shorts
    float* lbuf  = (float*)(qin + (size_t)8388608);  // [4][32768] f32 (wvb region)

    prep_kernel<<<1792, 256, 0, stream>>>(query, key, value, Wq, Wk, Wv, Wo,
        (const float4*)cache, qin, kin, vin, wqb, wkb, wvb, wob,
        (float4*)ncache, kbb, vtb, cnt);

    gemm64<<<dim3(8, 32, 3), 256, 0, stream>>>(qin, kin, vin, wqb, wkb, wvb,
        bq, bk, bv, ncache, qbuf, kbb, vtb, 0);

    attn_kernel<<<1024, 512, 0, stream>>>(qbuf, kbb, vtb, opart, lbuf, xb, cnt);

    gemm64<<<dim3(8, 32, 1), 256, 0, stream>>>(xb, nullptr, nullptr, wob, nullptr, nullptr,
        bo, nullptr, nullptr, out0, nullptr, nullptr, nullptr, 3);
}

// Round 13
// 120.769 us; speedup vs baseline: 4.1673x; 4.1673x over previous
//
#include <hip/hip_runtime.h>

typedef short short4s __attribute__((ext_vector_type(4)));
typedef short short8 __attribute__((ext_vector_type(8)));
typedef __bf16 bf16x8 __attribute__((ext_vector_type(8)));
typedef float f32x4 __attribute__((ext_vector_type(4)));

#define NFEAT 1024
#define HDIM  64
#define NHEAD 16
#define TC2   2048
#define QSCL  0.18033688011112043f   // log2(e)/8 folded into Q

__device__ __forceinline__ short f2bf(float f) {
    unsigned int u = __builtin_bit_cast(unsigned int, f);
    u += 0x7fffu + ((u >> 16) & 1u);
    return (short)(u >> 16);
}
__device__ __forceinline__ short f2bfq(float f) {
    __bf16 h = (__bf16)f;
    return __builtin_bit_cast(short, h);
}
__device__ __forceinline__ float bf2f(short s) {
    unsigned int u = ((unsigned int)(unsigned short)s) << 16;
    return __builtin_bit_cast(float, u);
}

__device__ __forceinline__ f32x4 mfma_bf16(short8 a, short8 b, f32x4 c) {
    return __builtin_amdgcn_mfma_f32_16x16x32_bf16(
        __builtin_bit_cast(bf16x8, a), __builtin_bit_cast(bf16x8, b), c, 0, 0, 0);
}

#define GLOAD16(gp, lp) __builtin_amdgcn_global_load_lds( \
    (const __attribute__((address_space(1))) void*)(gp),  \
    (__attribute__((address_space(3))) void*)(lp), 16, 0, 0)

// ---------------------------------------------------------------------------
// prep (R10 structure): conversions + cache chunk.
// ---------------------------------------------------------------------------
__global__ __launch_bounds__(256) void prep_kernel(
    const float* __restrict__ q, const float* __restrict__ k, const float* __restrict__ v,
    const float* __restrict__ Wq, const float* __restrict__ Wk,
    const float* __restrict__ Wv, const float* __restrict__ Wo,
    const float4* __restrict__ cache4,
    short* __restrict__ qin, short* __restrict__ kin, short* __restrict__ vin,
    short* __restrict__ wqb, short* __restrict__ wkb, short* __restrict__ wvb,
    short* __restrict__ wob,
    float4* __restrict__ nc4, short* __restrict__ kbb, short* __restrict__ vtb)
{
    __shared__ short Vt[64 * 72];
    const int b = blockIdx.x, tid = threadIdx.x;
    if (b < 1280) {
        const float* src; short* dst; size_t base;
        if (b < 256)        { src = q;  dst = qin; base = (size_t)b * 8192; }
        else if (b < 512)   { src = k;  dst = kin; base = (size_t)(b - 256) * 8192; }
        else if (b < 768)   { src = v;  dst = vin; base = (size_t)(b - 512) * 8192; }
        else if (b < 896)   { src = Wq; dst = wqb; base = (size_t)(b - 768) * 8192; }
        else if (b < 1024)  { src = Wk; dst = wkb; base = (size_t)(b - 896) * 8192; }
        else if (b < 1152)  { src = Wv; dst = wvb; base = (size_t)(b - 1024) * 8192; }
        else                { src = Wo; dst = wob; base = (size_t)(b - 1152) * 8192; }
        const size_t off = base + (size_t)tid * 8;
        float4 a[8];
#pragma unroll
        for (int s = 0; s < 4; ++s) {
            a[2*s]   = *(const float4*)(src + off + s * 2048);
            a[2*s+1] = *(const float4*)(src + off + s * 2048 + 4);
        }
#pragma unroll
        for (int s = 0; s < 4; ++s) {
            short8 o;
            o[0] = f2bf(a[2*s].x);   o[1] = f2bf(a[2*s].y);
            o[2] = f2bf(a[2*s].z);   o[3] = f2bf(a[2*s].w);
            o[4] = f2bf(a[2*s+1].x); o[5] = f2bf(a[2*s+1].y);
            o[6] = f2bf(a[2*s+1].z); o[7] = f2bf(a[2*s+1].w);
            *(short8*)(dst + off + s * 2048) = o;
        }
    } else {
        const int cb = b - 1280;                 // 0..511
        const int bh = cb >> 4, t0 = (cb & 15) * 64;
        const int col4 = tid & 31, r0 = tid >> 5;    // rows r0 + 8j
        const float4* src = cache4 + ((size_t)bh * 1024 + t0 + r0) * 32 + col4;
        float4* ncr = nc4 + ((size_t)bh * TC2 + t0 + r0) * 32 + col4;
        float4 a[8];
#pragma unroll
        for (int j = 0; j < 8; ++j) a[j] = src[j * 256];
#pragma unroll
        for (int j = 0; j < 8; ++j) ncr[j * 256] = a[j];
        if (col4 < 16) {                             // K half (c < 64)
#pragma unroll
            for (int j = 0; j < 8; ++j) {
                short4s kp;
                kp[0] = f2bf(a[j].x); kp[1] = f2bf(a[j].y);
                kp[2] = f2bf(a[j].z); kp[3] = f2bf(a[j].w);
                *(short4s*)&kbb[((size_t)bh * TC2 + t0 + r0 + 8 * j) * 64 + col4 * 4] = kp;
            }
        } else {                                     // V half -> LDS transpose
            const int d = (col4 - 16) * 4;
#pragma unroll
            for (int j = 0; j < 8; ++j) {
                int r = r0 + 8 * j;
                Vt[(d + 0) * 72 + r] = f2bf(a[j].x);
                Vt[(d + 1) * 72 + r] = f2bf(a[j].y);
                Vt[(d + 2) * 72 + r] = f2bf(a[j].z);
                Vt[(d + 3) * 72 + r] = f2bf(a[j].w);
            }
        }
        __syncthreads();
        const int d = tid >> 2, seg = (tid & 3) * 16;
        short* vd = &vtb[((size_t)bh * HDIM + d) * TC2 + t0 + seg];
        *(short8*)(vd)     = *(const short8*)&Vt[d * 72 + seg];
        *(short8*)(vd + 8) = *(const short8*)&Vt[d * 72 + seg + 8];
    }
}

// ---------------------------------------------------------------------------
// 64x128 GEMM, BK=128 (8 kt iterations, half the barriers of BK=64).
// LDS: As 16K + Bs 32K = 48KB -> 3 blocks/CU, matching the 3/CU grid.
// Staging: chunk c = it*256+tid -> row = it*16 + (tid>>4), colc = tid&15;
// LDS dst linear (wave-uniform base + lane*16B). y = A W^T + b.
// QKV: grid (8, 32, 3). O-proj: (8, 32, 1), base_mode=3.
// ---------------------------------------------------------------------------
__global__ __launch_bounds__(256) void gemm64(
    const short* __restrict__ A0, const short* __restrict__ A1, const short* __restrict__ A2,
    const short* __restrict__ W0, const short* __restrict__ W1, const short* __restrict__ W2,
    const float* __restrict__ b0, const float* __restrict__ b1, const float* __restrict__ b2,
    float* __restrict__ outf, short* __restrict__ qbuf, short* __restrict__ kbb,
    short* __restrict__ vtbp, int base_mode)
{
    __shared__ short As[64 * 128];
    __shared__ short Bs[128 * 128];

    int mode;
    const short *A, *W;
    const float* bias;
    if (base_mode == 3) { mode = 3; A = A0; W = W0; bias = b0; }
    else {
        mode = blockIdx.z;
        if (mode == 0)      { A = A0; W = W0; bias = b0; }
        else if (mode == 1) { A = A1; W = W1; bias = b1; }
        else                { A = A2; W = W2; bias = b2; }
    }

    const int tid = threadIdx.x, lane = tid & 63, w = tid >> 6;
    const int lr = lane & 15, lg = lane >> 4;
    const int bx = blockIdx.x, by = blockIdx.y;

    f32x4 acc[4][2];
#pragma unroll
    for (int m = 0; m < 4; ++m)
#pragma unroll
        for (int n = 0; n < 2; ++n) acc[m][n] = (f32x4){0.f, 0.f, 0.f, 0.f};

    const short* agBase = A + (size_t)(by * 64 + (tid >> 4)) * 1024 + (tid & 15) * 8;
    const short* bgBase = W + (size_t)(bx * 128 + (tid >> 4)) * 1024 + (tid & 15) * 8;
    short* asW = &As[w * 512];
    short* bsW = &Bs[w * 512];

    for (int kt = 0; kt < 8; ++kt) {
        const short* ag = agBase + kt * 128;
        const short* bg = bgBase + kt * 128;
#pragma unroll
        for (int it = 0; it < 4; ++it)
            GLOAD16(ag + (size_t)it * 16384, asW + it * 2048);
#pragma unroll
        for (int it = 0; it < 8; ++it)
            GLOAD16(bg + (size_t)it * 16384, bsW + it * 2048);
        __syncthreads();
#pragma unroll
        for (int kk = 0; kk < 4; ++kk) {
            short8 af[4], bf[2];
#pragma unroll
            for (int m = 0; m < 4; ++m)
                af[m] = *(const short8*)&As[(m * 16 + lr) * 128 + kk * 32 + lg * 8];
#pragma unroll
            for (int n = 0; n < 2; ++n)
                bf[n] = *(const short8*)&Bs[(w * 32 + n * 16 + lr) * 128 + kk * 32 + lg * 8];
#pragma unroll
            for (int m = 0; m < 4; ++m)
#pragma unroll
                for (int n = 0; n < 2; ++n)
                    acc[m][n] = mfma_bf16(af[m], bf[n], acc[m][n]);
        }
        __syncthreads();
    }

#pragma unroll
    for (int m = 0; m < 4; ++m) {
#pragma unroll
        for (int n = 0; n < 2; ++n) {
            const int cg = bx * 128 + w * 32 + n * 16 + lr;
            const int rg0 = by * 64 + m * 16 + lg * 4;
            const float bv = bias[cg];
            if (mode == 3) {
#pragma unroll
                for (int r = 0; r < 4; ++r)
                    outf[(size_t)(rg0 + r) * NFEAT + cg] = acc[m][n][r] + bv;
            } else {
                const int b = rg0 >> 10, t0 = rg0 & 1023;
                const int h = cg >> 6, d = cg & 63;
                const size_t bh = (size_t)b * NHEAD + h;
                if (mode == 0) {
#pragma unroll
                    for (int r = 0; r < 4; ++r)
                        qbuf[(bh * 1024 + t0 + r) * HDIM + d] = f2bf((acc[m][n][r] + bv) * QSCL);
                } else if (mode == 1) {
#pragma unroll
                    for (int r = 0; r < 4; ++r) {
                        float val = acc[m][n][r] + bv;
                        outf[(bh * TC2 + 1024 + t0 + r) * 128 + d] = val;
                        kbb[(bh * TC2 + 1024 + t0 + r) * HDIM + d] = f2bf(val);
                    }
                } else {
                    short4s pk;
#pragma unroll
                    for (int r = 0; r < 4; ++r) {
                        float val = acc[m][n][r] + bv;
                        outf[(bh * TC2 + 1024 + t0 + r) * 128 + 64 + d] = val;
                        pk[r] = f2bf(val);
                    }
                    *(short4s*)&vtbp[(bh * HDIM + d) * TC2 + 1024 + t0] = pk;
                }
            }
        }
    }
}

// ---------------------------------------------------------------------------
// Flash attention v7 (R10, proven): no online max, KV-split 4, 8 waves/block,
// async dbuf gload_lds staging with swizzled source.
// ---------------------------------------------------------------------------
__global__ __launch_bounds__(512) void attn_kernel(
    const short* __restrict__ qb, const short* __restrict__ kb,
    const short* __restrict__ vtb, short* __restrict__ opart, float* __restrict__ lbuf)
{
    __shared__ short Ks[2][64 * 64];
    __shared__ short Vs[2][64 * 64];
    __shared__ short Ps[8][16 * 32];

    const int tid = threadIdx.x, lane = tid & 63, w = tid >> 6;
    const int lr = lane & 15, lg = lane >> 4;
    const int b0 = blockIdx.x;
    const int xcd = b0 & 7, rest = b0 >> 3;           // 8 x 128
    const int unit = xcd + 8 * (rest & 15);           // 0..127 = bh*4 + quarter
    const int qt = rest >> 4;                         // 0..7
    const int bh = unit >> 2, quarter = unit & 3;
    const int xz = lr & 7;

    const short* qrow = qb + ((size_t)bh * 1024 + qt * 128 + w * 16 + lr) * HDIM + lg * 8;
    const short8 bq0 = *(const short8*)(qrow);
    const short8 bq1 = *(const short8*)(qrow + 32);

    const int srow = tid >> 3;
    const int scx = ((tid & 7) ^ (srow & 7)) * 8;
    const short* kgb = kb  + ((size_t)bh * TC2 + quarter * 512 + srow) * HDIM + scx;
    const short* vgb = vtb + ((size_t)bh * HDIM + srow) * TC2 + quarter * 512 + scx;
    short* kdst = &Ks[0][0] + w * 512;
    short* vdst = &Vs[0][0] + w * 512;

#define STAGE(bufsel, kvt_) do {                                         \
        const short* kg_ = kgb + (size_t)(kvt_) * 64 * HDIM;             \
        const short* vg_ = vgb + (kvt_) * 64;                            \
        GLOAD16(kg_, kdst + (bufsel) * 4096);                            \
        GLOAD16(vg_, vdst + (bufsel) * 4096);                            \
    } while (0)

    f32x4 accx[4];
#pragma unroll
    for (int i = 0; i < 4; ++i) accx[i] = (f32x4){0.f, 0.f, 0.f, 0.f};
    float lsp = 0.f;                                  // per-lane l partial
    short* pw = &Ps[w][0];

    STAGE(0, 0);
    __syncthreads();

    int cur = 0;
    for (int kvt = 0; kvt < 8; ++kvt) {
        if (kvt < 7) STAGE(cur ^ 1, kvt + 1);
        const short* Kc = &Ks[cur][0];
        const short* Vc = &Vs[cur][0];

        // ---- S^T = K Q^T ----
        f32x4 s[4];
#pragma unroll
        for (int n = 0; n < 4; ++n) {
            const short* kt = Kc + (n * 16 + lr) * 64;
            short8 k0 = *(const short8*)&kt[(lg ^ xz) * 8];
            short8 k1 = *(const short8*)&kt[((4 + lg) ^ xz) * 8];
            s[n] = (f32x4){0.f, 0.f, 0.f, 0.f};
            s[n] = mfma_bf16(k0, bq0, s[n]);
            s[n] = mfma_bf16(k1, bq1, s[n]);
        }

        // ---- P = exp2(S), per-lane l partial ----
        float p[4][4];
#pragma unroll
        for (int n = 0; n < 4; ++n)
#pragma unroll
            for (int r = 0; r < 4; ++r) p[n][r] = __builtin_amdgcn_exp2f(s[n][r]);
        float sm[8];
#pragma unroll
        for (int i = 0; i < 8; ++i) sm[i] = p[i >> 1][(i & 1) * 2] + p[i >> 1][(i & 1) * 2 + 1];
        lsp += ((sm[0] + sm[1]) + (sm[2] + sm[3])) + ((sm[4] + sm[5]) + (sm[6] + sm[7]));

        // ---- PV per k-slice ----
#pragma unroll
        for (int ks = 0; ks < 2; ++ks) {
            __builtin_amdgcn_sched_barrier(0);
#pragma unroll
            for (int np = 0; np < 2; ++np) {
                int n = 2 * ks + np;
                short4s pk;
                pk[0] = f2bfq(p[n][0]); pk[1] = f2bfq(p[n][1]);
                pk[2] = f2bfq(p[n][2]); pk[3] = f2bfq(p[n][3]);
                int slot = (2 * np + (lg >> 1)) ^ (lr & 3);
                *(short4s*)&pw[lr * 32 + slot * 8 + (lg & 1) * 4] = pk;
            }
            short8 ap = *(const short8*)&pw[lr * 32 + (lg ^ (lr & 3)) * 8];
#pragma unroll
            for (int nd = 0; nd < 4; ++nd) {
                const short* vt = Vc + (nd * 16 + lr) * 64;
                short8 vf = *(const short8*)&vt[((ks * 4 + lg) ^ xz) * 8];
                accx[nd] = mfma_bf16(ap, vf, accx[nd]);
            }
        }

        __syncthreads();
        cur ^= 1;
    }

    // ---- epilogue ----
    float ls = lsp;
    ls += __shfl_xor(ls, 16);
    ls += __shfl_xor(ls, 32);
    const size_t rbase = (size_t)quarter * 32768 + (size_t)bh * 1024 + qt * 128 + w * 16;
#pragma unroll
    for (int nd = 0; nd < 4; ++nd)
#pragma unroll
        for (int r = 0; r < 4; ++r)
            opart[(rbase + lg * 4 + r) * 64 + nd * 16 + lr] = f2bfq(accx[nd][r]);
    if (lg == 0) lbuf[rbase + lr] = ls;
#undef STAGE
}

// ---------------------------------------------------------------------------
// Combine the four kv-quarters: out = (sum_i O_i) / (sum_i l_i).
// ---------------------------------------------------------------------------
__global__ __launch_bounds__(256) void combine_kernel(
    const short* __restrict__ opart, const float* __restrict__ lbuf,
    short* __restrict__ xb)
{
    int idx = blockIdx.x * 256 + threadIdx.x;    // 262144 = 32768 rows x 8 segs
    int r = idx >> 3, d8 = (idx & 7) * 8;
    float l = lbuf[r] + lbuf[32768 + r] + lbuf[65536 + r] + lbuf[98304 + r];
    float acc[8];
#pragma unroll
    for (int j = 0; j < 8; ++j) acc[j] = 0.f;
#pragma unroll
    for (int i = 0; i < 4; ++i) {
        short8 op = *(const short8*)&opart[((size_t)i * 32768 + r) * 64 + d8];
#pragma unroll
        for (int j = 0; j < 8; ++j) acc[j] += bf2f(op[j]);
    }
    float inv = 1.0f / l;
    short8 o;
#pragma unroll
    for (int j = 0; j < 8; ++j) o[j] = f2bfq(acc[j] * inv);
    int bh = r >> 10, tq = r & 1023;
    int b = bh >> 4, h = bh & 15;
    *(short8*)&xb[((size_t)(b * 1024 + tq)) * NFEAT + h * 64 + d8] = o;
}

// ---------------------------------------------------------------------------
extern "C" void kernel_launch(void* const* d_in, const int* in_sizes, int n_in,
                              void* d_out, int out_size, void* d_ws, size_t ws_size,
                              hipStream_t stream) {
    const float* query = (const float*)d_in[0];
    const float* key   = (const float*)d_in[1];
    const float* value = (const float*)d_in[2];
    const float* cache = (const float*)d_in[3];
    const float* Wq = (const float*)d_in[4];
    const float* bq = (const float*)d_in[5];
    const float* Wk = (const float*)d_in[6];
    const float* bk = (const float*)d_in[7];
    const float* Wv = (const float*)d_in[8];
    const float* bv = (const float*)d_in[9];
    const float* Wo = (const float*)d_in[10];
    const float* bo = (const float*)d_in[11];

    float* out0   = (float*)d_out;
    float* ncache = out0 + (size_t)2 * 1024 * 1024;

    short* qin = (short*)d_ws;                       // 0      (2M shorts)
    short* kin = qin + (size_t)2097152;              // 2M
    short* vin = kin + (size_t)2097152;              // 4M
    short* wqb = vin + (size_t)2097152;              // 6M
    short* wkb = wqb + (size_t)1048576;              // 7M
    short* wvb = wkb + (size_t)1048576;              // 8M
    short* wob = wvb + (size_t)1048576;              // 9M
    short* qbuf = wob + (size_t)1048576;             // 10M (2M)
    short* kbb  = qbuf + (size_t)2097152;            // 12M (4M)
    short* vtb  = kbb  + (size_t)4194304;            // 16M (4M) -> 20M total
    // Overlays (regions dead by the time attn runs):
    short* opart = (short*)d_ws;                     // [4][32768][64] bf16 = 8M shorts (qin..wkb)
    float* lbuf  = (float*)(qin + (size_t)8388608);  // [4][32768] f32 (wvb region)
    short* xb    = qbuf;                             // combine output (Q dead then)

    prep_kernel<<<1792, 256, 0, stream>>>(query, key, value, Wq, Wk, Wv, Wo,
        (const float4*)cache, qin, kin, vin, wqb, wkb, wvb, wob,
        (float4*)ncache, kbb, vtb);

    gemm64<<<dim3(8, 32, 3), 256, 0, stream>>>(qin, kin, vin, wqb, wkb, wvb,
        bq, bk, bv, ncache, qbuf, kbb, vtb, 0);

    attn_kernel<<<1024, 512, 0, stream>>>(qbuf, kbb, vtb, opart, lbuf);

    combine_kernel<<<1024, 256, 0, stream>>>(opart, lbuf, xb);

    gemm64<<<dim3(8, 32, 1), 256, 0, stream>>>(xb, nullptr, nullptr, wob, nullptr, nullptr,
        bo, nullptr, nullptr, out0, nullptr, nullptr, nullptr, 3);
}

// Round 14
// 99.613 us; speedup vs baseline: 5.0524x; 1.2124x over previous
//
#include <hip/hip_runtime.h>

typedef short short4s __attribute__((ext_vector_type(4)));
typedef short short8 __attribute__((ext_vector_type(8)));
typedef __bf16 bf16x8 __attribute__((ext_vector_type(8)));
typedef float f32x4 __attribute__((ext_vector_type(4)));

#define NFEAT 1024
#define HDIM  64
#define NHEAD 16
#define TC2   2048
#define QSCL  0.18033688011112043f   // log2(e)/8 folded into Q

__device__ __forceinline__ short f2bf(float f) {
    unsigned int u = __builtin_bit_cast(unsigned int, f);
    u += 0x7fffu + ((u >> 16) & 1u);
    return (short)(u >> 16);
}
__device__ __forceinline__ short f2bfq(float f) {
    __bf16 h = (__bf16)f;
    return __builtin_bit_cast(short, h);
}
__device__ __forceinline__ float bf2f(short s) {
    unsigned int u = ((unsigned int)(unsigned short)s) << 16;
    return __builtin_bit_cast(float, u);
}

__device__ __forceinline__ f32x4 mfma_bf16(short8 a, short8 b, f32x4 c) {
    return __builtin_amdgcn_mfma_f32_16x16x32_bf16(
        __builtin_bit_cast(bf16x8, a), __builtin_bit_cast(bf16x8, b), c, 0, 0, 0);
}

#define GLOAD16(gp, lp) __builtin_amdgcn_global_load_lds( \
    (const __attribute__((address_space(1))) void*)(gp),  \
    (__attribute__((address_space(3))) void*)(lp), 16, 0, 0)

// ---------------------------------------------------------------------------
// prep (R10): conversions + cache chunk.
// ---------------------------------------------------------------------------
__global__ __launch_bounds__(256) void prep_kernel(
    const float* __restrict__ q, const float* __restrict__ k, const float* __restrict__ v,
    const float* __restrict__ Wq, const float* __restrict__ Wk,
    const float* __restrict__ Wv, const float* __restrict__ Wo,
    const float4* __restrict__ cache4,
    short* __restrict__ qin, short* __restrict__ kin, short* __restrict__ vin,
    short* __restrict__ wqb, short* __restrict__ wkb, short* __restrict__ wvb,
    short* __restrict__ wob,
    float4* __restrict__ nc4, short* __restrict__ kbb, short* __restrict__ vtb)
{
    __shared__ short Vt[64 * 72];
    const int b = blockIdx.x, tid = threadIdx.x;
    if (b < 1280) {
        const float* src; short* dst; size_t base;
        if (b < 256)        { src = q;  dst = qin; base = (size_t)b * 8192; }
        else if (b < 512)   { src = k;  dst = kin; base = (size_t)(b - 256) * 8192; }
        else if (b < 768)   { src = v;  dst = vin; base = (size_t)(b - 512) * 8192; }
        else if (b < 896)   { src = Wq; dst = wqb; base = (size_t)(b - 768) * 8192; }
        else if (b < 1024)  { src = Wk; dst = wkb; base = (size_t)(b - 896) * 8192; }
        else if (b < 1152)  { src = Wv; dst = wvb; base = (size_t)(b - 1024) * 8192; }
        else                { src = Wo; dst = wob; base = (size_t)(b - 1152) * 8192; }
        const size_t off = base + (size_t)tid * 8;
        float4 a[8];
#pragma unroll
        for (int s = 0; s < 4; ++s) {
            a[2*s]   = *(const float4*)(src + off + s * 2048);
            a[2*s+1] = *(const float4*)(src + off + s * 2048 + 4);
        }
#pragma unroll
        for (int s = 0; s < 4; ++s) {
            short8 o;
            o[0] = f2bf(a[2*s].x);   o[1] = f2bf(a[2*s].y);
            o[2] = f2bf(a[2*s].z);   o[3] = f2bf(a[2*s].w);
            o[4] = f2bf(a[2*s+1].x); o[5] = f2bf(a[2*s+1].y);
            o[6] = f2bf(a[2*s+1].z); o[7] = f2bf(a[2*s+1].w);
            *(short8*)(dst + off + s * 2048) = o;
        }
    } else {
        const int cb = b - 1280;                 // 0..511
        const int bh = cb >> 4, t0 = (cb & 15) * 64;
        const int col4 = tid & 31, r0 = tid >> 5;    // rows r0 + 8j
        const float4* src = cache4 + ((size_t)bh * 1024 + t0 + r0) * 32 + col4;
        float4* ncr = nc4 + ((size_t)bh * TC2 + t0 + r0) * 32 + col4;
        float4 a[8];
#pragma unroll
        for (int j = 0; j < 8; ++j) a[j] = src[j * 256];
#pragma unroll
        for (int j = 0; j < 8; ++j) ncr[j * 256] = a[j];
        if (col4 < 16) {                             // K half (c < 64)
#pragma unroll
            for (int j = 0; j < 8; ++j) {
                short4s kp;
                kp[0] = f2bf(a[j].x); kp[1] = f2bf(a[j].y);
                kp[2] = f2bf(a[j].z); kp[3] = f2bf(a[j].w);
                *(short4s*)&kbb[((size_t)bh * TC2 + t0 + r0 + 8 * j) * 64 + col4 * 4] = kp;
            }
        } else {                                     // V half -> LDS transpose
            const int d = (col4 - 16) * 4;
#pragma unroll
            for (int j = 0; j < 8; ++j) {
                int r = r0 + 8 * j;
                Vt[(d + 0) * 72 + r] = f2bf(a[j].x);
                Vt[(d + 1) * 72 + r] = f2bf(a[j].y);
                Vt[(d + 2) * 72 + r] = f2bf(a[j].z);
                Vt[(d + 3) * 72 + r] = f2bf(a[j].w);
            }
        }
        __syncthreads();
        const int d = tid >> 2, seg = (tid & 3) * 16;
        short* vd = &vtb[((size_t)bh * HDIM + d) * TC2 + t0 + seg];
        *(short8*)(vd)     = *(const short8*)&Vt[d * 72 + seg];
        *(short8*)(vd + 8) = *(const short8*)&Vt[d * 72 + seg + 8];
    }
}

// ---------------------------------------------------------------------------
// 64x128 GEMM (R10 structure, BK=64) + XCD-affinity block swizzle.
// Linear block id remapped bijectively: newid = (orig%8)*chunk + orig/8,
// so each XCD's L2 sees one contiguous (mode, by-range, all-bx) chunk:
// 12 A-panels (1.5MB) + full W (2MB) = 3.5MB < 4MB per-XCD L2.
// QKV: grid (8, 32, 3). O-proj: (8, 32, 1), base_mode=3.
// ---------------------------------------------------------------------------
__global__ __launch_bounds__(256) void gemm64(
    const short* __restrict__ A0, const short* __restrict__ A1, const short* __restrict__ A2,
    const short* __restrict__ W0, const short* __restrict__ W1, const short* __restrict__ W2,
    const float* __restrict__ b0, const float* __restrict__ b1, const float* __restrict__ b2,
    float* __restrict__ outf, short* __restrict__ qbuf, short* __restrict__ kbb,
    short* __restrict__ vtbp, int base_mode)
{
    __shared__ short As[64 * 64];
    __shared__ short Bs[128 * 64];

    // ---- XCD swizzle (bijective: nwg divisible by 8) ----
    const int orig = (blockIdx.z * gridDim.y + blockIdx.y) * gridDim.x + blockIdx.x;
    const int chunk = (gridDim.x * gridDim.y * gridDim.z) >> 3;
    const int newid = (orig & 7) * chunk + (orig >> 3);
    const int rem = newid & 255;
    const int by = rem >> 3, bx = rem & 7;

    int mode;
    const short *A, *W;
    const float* bias;
    if (base_mode == 3) { mode = 3; A = A0; W = W0; bias = b0; }
    else {
        mode = newid >> 8;
        if (mode == 0)      { A = A0; W = W0; bias = b0; }
        else if (mode == 1) { A = A1; W = W1; bias = b1; }
        else                { A = A2; W = W2; bias = b2; }
    }

    const int tid = threadIdx.x, lane = tid & 63, w = tid >> 6;
    const int lr = lane & 15, lg = lane >> 4;

    f32x4 acc[4][2];
#pragma unroll
    for (int m = 0; m < 4; ++m)
#pragma unroll
        for (int n = 0; n < 2; ++n) acc[m][n] = (f32x4){0.f, 0.f, 0.f, 0.f};

    const short* agBase = A + (size_t)(by * 64 + w * 16 + (lane >> 3)) * 1024 + (lane & 7) * 8;
    const short* bgBase = W + (size_t)(bx * 128 + w * 32 + (lane >> 3)) * 1024 + (lane & 7) * 8;
    short* asW = &As[w * 1024];
    short* bsW = &Bs[w * 2048];

    for (int kt = 0; kt < 16; ++kt) {
        const short* ag = agBase + kt * 64;
        const short* bg = bgBase + kt * 64;
        GLOAD16(ag,          asW);
        GLOAD16(ag + 8192,   asW + 512);
        GLOAD16(bg,          bsW);
        GLOAD16(bg + 8192,   bsW + 512);
        GLOAD16(bg + 16384,  bsW + 1024);
        GLOAD16(bg + 24576,  bsW + 1536);
        __syncthreads();
#pragma unroll
        for (int kk = 0; kk < 2; ++kk) {
            short8 af[4], bf[2];
#pragma unroll
            for (int m = 0; m < 4; ++m)
                af[m] = *(const short8*)&As[(m * 16 + lr) * 64 + kk * 32 + lg * 8];
#pragma unroll
            for (int n = 0; n < 2; ++n)
                bf[n] = *(const short8*)&Bs[(w * 32 + n * 16 + lr) * 64 + kk * 32 + lg * 8];
#pragma unroll
            for (int m = 0; m < 4; ++m)
#pragma unroll
                for (int n = 0; n < 2; ++n)
                    acc[m][n] = mfma_bf16(af[m], bf[n], acc[m][n]);
        }
        __syncthreads();
    }

#pragma unroll
    for (int m = 0; m < 4; ++m) {
#pragma unroll
        for (int n = 0; n < 2; ++n) {
            const int cg = bx * 128 + w * 32 + n * 16 + lr;
            const int rg0 = by * 64 + m * 16 + lg * 4;
            const float bv = bias[cg];
            if (mode == 3) {
#pragma unroll
                for (int r = 0; r < 4; ++r)
                    outf[(size_t)(rg0 + r) * NFEAT + cg] = acc[m][n][r] + bv;
            } else {
                const int b = rg0 >> 10, t0 = rg0 & 1023;
                const int h = cg >> 6, d = cg & 63;
                const size_t bh = (size_t)b * NHEAD + h;
                if (mode == 0) {
#pragma unroll
                    for (int r = 0; r < 4; ++r)
                        qbuf[(bh * 1024 + t0 + r) * HDIM + d] = f2bf((acc[m][n][r] + bv) * QSCL);
                } else if (mode == 1) {
#pragma unroll
                    for (int r = 0; r < 4; ++r) {
                        float val = acc[m][n][r] + bv;
                        outf[(bh * TC2 + 1024 + t0 + r) * 128 + d] = val;
                        kbb[(bh * TC2 + 1024 + t0 + r) * HDIM + d] = f2bf(val);
                    }
                } else {
                    short4s pk;
#pragma unroll
                    for (int r = 0; r < 4; ++r) {
                        float val = acc[m][n][r] + bv;
                        outf[(bh * TC2 + 1024 + t0 + r) * 128 + 64 + d] = val;
                        pk[r] = f2bf(val);
                    }
                    *(short4s*)&vtbp[(bh * HDIM + d) * TC2 + 1024 + t0] = pk;
                }
            }
        }
    }
}

// ---------------------------------------------------------------------------
// Flash attention v7 (R10, proven): no online max, KV-split 4, 8 waves/block,
// async dbuf gload_lds staging with swizzled source.
// ---------------------------------------------------------------------------
__global__ __launch_bounds__(512) void attn_kernel(
    const short* __restrict__ qb, const short* __restrict__ kb,
    const short* __restrict__ vtb, short* __restrict__ opart, float* __restrict__ lbuf)
{
    __shared__ short Ks[2][64 * 64];
    __shared__ short Vs[2][64 * 64];
    __shared__ short Ps[8][16 * 32];

    const int tid = threadIdx.x, lane = tid & 63, w = tid >> 6;
    const int lr = lane & 15, lg = lane >> 4;
    const int b0 = blockIdx.x;
    const int xcd = b0 & 7, rest = b0 >> 3;           // 8 x 128
    const int unit = xcd + 8 * (rest & 15);           // 0..127 = bh*4 + quarter
    const int qt = rest >> 4;                         // 0..7
    const int bh = unit >> 2, quarter = unit & 3;
    const int xz = lr & 7;

    const short* qrow = qb + ((size_t)bh * 1024 + qt * 128 + w * 16 + lr) * HDIM + lg * 8;
    const short8 bq0 = *(const short8*)(qrow);
    const short8 bq1 = *(const short8*)(qrow + 32);

    const int srow = tid >> 3;
    const int scx = ((tid & 7) ^ (srow & 7)) * 8;
    const short* kgb = kb  + ((size_t)bh * TC2 + quarter * 512 + srow) * HDIM + scx;
    const short* vgb = vtb + ((size_t)bh * HDIM + srow) * TC2 + quarter * 512 + scx;
    short* kdst = &Ks[0][0] + w * 512;
    short* vdst = &Vs[0][0] + w * 512;

#define STAGE(bufsel, kvt_) do {                                         \
        const short* kg_ = kgb + (size_t)(kvt_) * 64 * HDIM;             \
        const short* vg_ = vgb + (kvt_) * 64;                            \
        GLOAD16(kg_, kdst + (bufsel) * 4096);                            \
        GLOAD16(vg_, vdst + (bufsel) * 4096);                            \
    } while (0)

    f32x4 accx[4];
#pragma unroll
    for (int i = 0; i < 4; ++i) accx[i] = (f32x4){0.f, 0.f, 0.f, 0.f};
    float lsp = 0.f;                                  // per-lane l partial
    short* pw = &Ps[w][0];

    STAGE(0, 0);
    __syncthreads();

    int cur = 0;
    for (int kvt = 0; kvt < 8; ++kvt) {
        if (kvt < 7) STAGE(cur ^ 1, kvt + 1);
        const short* Kc = &Ks[cur][0];
        const short* Vc = &Vs[cur][0];

        // ---- S^T = K Q^T ----
        f32x4 s[4];
#pragma unroll
        for (int n = 0; n < 4; ++n) {
            const short* kt = Kc + (n * 16 + lr) * 64;
            short8 k0 = *(const short8*)&kt[(lg ^ xz) * 8];
            short8 k1 = *(const short8*)&kt[((4 + lg) ^ xz) * 8];
            s[n] = (f32x4){0.f, 0.f, 0.f, 0.f};
            s[n] = mfma_bf16(k0, bq0, s[n]);
            s[n] = mfma_bf16(k1, bq1, s[n]);
        }

        // ---- P = exp2(S), per-lane l partial ----
        float p[4][4];
#pragma unroll
        for (int n = 0; n < 4; ++n)
#pragma unroll
            for (int r = 0; r < 4; ++r) p[n][r] = __builtin_amdgcn_exp2f(s[n][r]);
        float sm[8];
#pragma unroll
        for (int i = 0; i < 8; ++i) sm[i] = p[i >> 1][(i & 1) * 2] + p[i >> 1][(i & 1) * 2 + 1];
        lsp += ((sm[0] + sm[1]) + (sm[2] + sm[3])) + ((sm[4] + sm[5]) + (sm[6] + sm[7]));

        // ---- PV per k-slice ----
#pragma unroll
        for (int ks = 0; ks < 2; ++ks) {
            __builtin_amdgcn_sched_barrier(0);
#pragma unroll
            for (int np = 0; np < 2; ++np) {
                int n = 2 * ks + np;
                short4s pk;
                pk[0] = f2bfq(p[n][0]); pk[1] = f2bfq(p[n][1]);
                pk[2] = f2bfq(p[n][2]); pk[3] = f2bfq(p[n][3]);
                int slot = (2 * np + (lg >> 1)) ^ (lr & 3);
                *(short4s*)&pw[lr * 32 + slot * 8 + (lg & 1) * 4] = pk;
            }
            short8 ap = *(const short8*)&pw[lr * 32 + (lg ^ (lr & 3)) * 8];
#pragma unroll
            for (int nd = 0; nd < 4; ++nd) {
                const short* vt = Vc + (nd * 16 + lr) * 64;
                short8 vf = *(const short8*)&vt[((ks * 4 + lg) ^ xz) * 8];
                accx[nd] = mfma_bf16(ap, vf, accx[nd]);
            }
        }

        __syncthreads();
        cur ^= 1;
    }

    // ---- epilogue ----
    float ls = lsp;
    ls += __shfl_xor(ls, 16);
    ls += __shfl_xor(ls, 32);
    const size_t rbase = (size_t)quarter * 32768 + (size_t)bh * 1024 + qt * 128 + w * 16;
#pragma unroll
    for (int nd = 0; nd < 4; ++nd)
#pragma unroll
        for (int r = 0; r < 4; ++r)
            opart[(rbase + lg * 4 + r) * 64 + nd * 16 + lr] = f2bfq(accx[nd][r]);
    if (lg == 0) lbuf[rbase + lr] = ls;
#undef STAGE
}

// ---------------------------------------------------------------------------
// Combine the four kv-quarters: out = (sum_i O_i) / (sum_i l_i).
// ---------------------------------------------------------------------------
__global__ __launch_bounds__(256) void combine_kernel(
    const short* __restrict__ opart, const float* __restrict__ lbuf,
    short* __restrict__ xb)
{
    int idx = blockIdx.x * 256 + threadIdx.x;    // 262144 = 32768 rows x 8 segs
    int r = idx >> 3, d8 = (idx & 7) * 8;
    float l = lbuf[r] + lbuf[32768 + r] + lbuf[65536 + r] + lbuf[98304 + r];
    float acc[8];
#pragma unroll
    for (int j = 0; j < 8; ++j) acc[j] = 0.f;
#pragma unroll
    for (int i = 0; i < 4; ++i) {
        short8 op = *(const short8*)&opart[((size_t)i * 32768 + r) * 64 + d8];
#pragma unroll
        for (int j = 0; j < 8; ++j) acc[j] += bf2f(op[j]);
    }
    float inv = 1.0f / l;
    short8 o;
#pragma unroll
    for (int j = 0; j < 8; ++j) o[j] = f2bfq(acc[j] * inv);
    int bh = r >> 10, tq = r & 1023;
    int b = bh >> 4, h = bh & 15;
    *(short8*)&xb[((size_t)(b * 1024 + tq)) * NFEAT + h * 64 + d8] = o;
}

// ---------------------------------------------------------------------------
extern "C" void kernel_launch(void* const* d_in, const int* in_sizes, int n_in,
                              void* d_out, int out_size, void* d_ws, size_t ws_size,
                              hipStream_t stream) {
    const float* query = (const float*)d_in[0];
    const float* key   = (const float*)d_in[1];
    const float* value = (const float*)d_in[2];
    const float* cache = (const float*)d_in[3];
    const float* Wq = (const float*)d_in[4];
    const float* bq = (const float*)d_in[5];
    const float* Wk = (const float*)d_in[6];
    const float* bk = (const float*)d_in[7];
    const float* Wv = (const float*)d_in[8];
    const float* bv = (const float*)d_in[9];
    const float* Wo = (const float*)d_in[10];
    const float* bo = (const float*)d_in[11];

    float* out0   = (float*)d_out;
    float* ncache = out0 + (size_t)2 * 1024 * 1024;

    short* qin = (short*)d_ws;                       // 0      (2M shorts)
    short* kin = qin + (size_t)2097152;              // 2M
    short* vin = kin + (size_t)2097152;              // 4M
    short* wqb = vin + (size_t)2097152;              // 6M
    short* wkb = wqb + (size_t)1048576;              // 7M
    short* wvb = wkb + (size_t)1048576;              // 8M
    short* wob = wvb + (size_t)1048576;              // 9M
    short* qbuf = wob + (size_t)1048576;             // 10M (2M)
    short* kbb  = qbuf + (size_t)2097152;            // 12M (4M)
    short* vtb  = kbb  + (size_t)4194304;            // 16M (4M) -> 20M total
    // Overlays (regions dead by the time attn runs):
    short* opart = (short*)d_ws;                     // [4][32768][64] bf16 = 8M shorts (qin..wkb)
    float* lbuf  = (float*)(qin + (size_t)8388608);  // [4][32768] f32 (wvb region)
    short* xb    = qbuf;                             // combine output (Q dead then)

    prep_kernel<<<1792, 256, 0, stream>>>(query, key, value, Wq, Wk, Wv, Wo,
        (const float4*)cache, qin, kin, vin, wqb, wkb, wvb, wob,
        (float4*)ncache, kbb, vtb);

    gemm64<<<dim3(8, 32, 3), 256, 0, stream>>>(qin, kin, vin, wqb, wkb, wvb,
        bq, bk, bv, ncache, qbuf, kbb, vtb, 0);

    attn_kernel<<<1024, 512, 0, stream>>>(qbuf, kbb, vtb, opart, lbuf);

    combine_kernel<<<1024, 256, 0, stream>>>(opart, lbuf, xb);

    gemm64<<<dim3(8, 32, 1), 256, 0, stream>>>(xb, nullptr, nullptr, wob, nullptr, nullptr,
        bo, nullptr, nullptr, out0, nullptr, nullptr, nullptr, 3);
}